// Round 1
// baseline (716.623 us; speedup 1.0000x reference)
//
#include <hip/hip_runtime.h>
#include <math.h>

#define D_MODEL 1024
#define N_HEADS 16
#define HEAD_DIM 64
#define BATCH 2
#define SEQ 2048
#define WIN_L 127
#define WIN_R 128

// ---------------------------------------------------------------------------
// SGEMM (NT): C[m][n] = sum_k A[m*K+k] * B[n*K+k]  (+ bias[n])
// A: MxK row-major, B: NxK row-major (we dot rows of A with rows of B).
// BM=BN=128, BK=16, 256 threads, 8x8 micro-tile (4+4 split layout).
// ---------------------------------------------------------------------------
template<bool HAS_BIAS>
__global__ __launch_bounds__(256, 2)
void sgemm_nt(const float* __restrict__ A, const float* __restrict__ B,
              const float* __restrict__ bias, float* __restrict__ C,
              int M, int N, int K)
{
    __shared__ float As[16][132];   // [k][m], +4 pad keeps float4 align, ~2-way banks
    __shared__ float Bs[16][132];   // [k][n]

    const int tid = threadIdx.x;
    const int tx  = tid & 15;        // n micro index
    const int ty  = tid >> 4;        // m micro index
    const int m0  = blockIdx.y * 128;
    const int n0  = blockIdx.x * 128;

    const int lrow = tid >> 2;           // 0..63
    const int lcol = (tid & 3) << 2;     // 0,4,8,12

    const float* Ap = A + (size_t)(m0 + lrow) * K + lcol;
    const float* Bp = B + (size_t)(n0 + lrow) * K + lcol;

    float acc[8][8];
#pragma unroll
    for (int i = 0; i < 8; ++i)
#pragma unroll
        for (int j = 0; j < 8; ++j) acc[i][j] = 0.0f;

    for (int k0 = 0; k0 < K; k0 += 16) {
        float4 a0 = *(const float4*)(Ap + k0);
        float4 a1 = *(const float4*)(Ap + (size_t)64 * K + k0);
        float4 b0 = *(const float4*)(Bp + k0);
        float4 b1 = *(const float4*)(Bp + (size_t)64 * K + k0);
        __syncthreads();   // protect previous iteration's LDS reads
        {
            float a0v[4] = {a0.x, a0.y, a0.z, a0.w};
            float a1v[4] = {a1.x, a1.y, a1.z, a1.w};
            float b0v[4] = {b0.x, b0.y, b0.z, b0.w};
            float b1v[4] = {b1.x, b1.y, b1.z, b1.w};
#pragma unroll
            for (int j = 0; j < 4; ++j) {
                As[lcol + j][lrow]      = a0v[j];
                As[lcol + j][lrow + 64] = a1v[j];
                Bs[lcol + j][lrow]      = b0v[j];
                Bs[lcol + j][lrow + 64] = b1v[j];
            }
        }
        __syncthreads();
#pragma unroll
        for (int kk = 0; kk < 16; ++kk) {
            float4 aq0 = *(const float4*)&As[kk][ty * 4];
            float4 aq1 = *(const float4*)&As[kk][64 + ty * 4];
            float4 bq0 = *(const float4*)&Bs[kk][tx * 4];
            float4 bq1 = *(const float4*)&Bs[kk][64 + tx * 4];
            float ar[8] = {aq0.x, aq0.y, aq0.z, aq0.w, aq1.x, aq1.y, aq1.z, aq1.w};
            float br[8] = {bq0.x, bq0.y, bq0.z, bq0.w, bq1.x, bq1.y, bq1.z, bq1.w};
#pragma unroll
            for (int i = 0; i < 8; ++i)
#pragma unroll
                for (int j = 0; j < 8; ++j)
                    acc[i][j] = fmaf(ar[i], br[j], acc[i][j]);
        }
    }

    float4 bv0 = make_float4(0.f, 0.f, 0.f, 0.f);
    float4 bv1 = make_float4(0.f, 0.f, 0.f, 0.f);
    if (HAS_BIAS) {
        bv0 = *(const float4*)&bias[n0 + tx * 4];
        bv1 = *(const float4*)&bias[n0 + 64 + tx * 4];
    }
#pragma unroll
    for (int i = 0; i < 8; ++i) {
        int r = m0 + ((i < 4) ? (ty * 4 + i) : (64 + ty * 4 + (i - 4)));
        float4 o0 = make_float4(acc[i][0] + bv0.x, acc[i][1] + bv0.y,
                                acc[i][2] + bv0.z, acc[i][3] + bv0.w);
        float4 o1 = make_float4(acc[i][4] + bv1.x, acc[i][5] + bv1.y,
                                acc[i][6] + bv1.z, acc[i][7] + bv1.w);
        *(float4*)&C[(size_t)r * N + n0 + tx * 4]      = o0;
        *(float4*)&C[(size_t)r * N + n0 + 64 + tx * 4] = o1;
    }
}

// ---------------------------------------------------------------------------
// RoPE in-place on q and k slices of qkv[(n,t), 3, H, HD].
// Pair (d, d+32) per head, angle = t * 10000^(-d/32), d in [0,32).
// ---------------------------------------------------------------------------
__global__ __launch_bounds__(256)
void rope_qk(float* __restrict__ qkv)
{
    const int t = blockIdx.x;
    const int n = blockIdx.y;
    const int tid = threadIdx.x;
#pragma unroll
    for (int idx = tid; idx < 1024; idx += 256) {
        const int which = idx >> 9;       // 0 = q, 1 = k
        const int p = idx & 511;
        const int h = p >> 5;
        const int d = p & 31;
        float invf = powf(10000.0f, -(float)d * (1.0f / 32.0f));
        float ang = (float)t * invf;
        float s, c;
        sincosf(ang, &s, &c);
        float* base = qkv + ((size_t)(n * SEQ + t) * 3 + which) * D_MODEL + h * HEAD_DIM + d;
        float x1 = base[0];
        float x2 = base[32];
        base[0]  = x1 * c - x2 * s;
        base[32] = x2 * c + x1 * s;
    }
}

// ---------------------------------------------------------------------------
// Banded attention. Block = (16 queries, one (n,h)). Band union <= 271 keys,
// processed in 64-key chunks staged in LDS. Scores kept in LDS (16 x 320),
// shuffle softmax per row, then PV over V chunks.
// ---------------------------------------------------------------------------
__global__ __launch_bounds__(256)
void attn_band(const float* __restrict__ qkv, float* __restrict__ attn)
{
    const int TQ = 16;
    __shared__ float Qs[TQ][64];
    __shared__ float Kch[64][68];
    __shared__ float Vch[64][68];
    __shared__ float Sc[TQ][320];

    const int tid = threadIdx.x;
    const int t0 = blockIdx.x * TQ;
    const int h  = blockIdx.y;
    const int n  = blockIdx.z;

    const int lo = max(0, t0 - WIN_L);
    const int hi = min(SEQ, t0 + TQ - 1 + WIN_R + 1);   // exclusive
    const int nch = (hi - lo + 63) >> 6;

    const int qi  = tid >> 4;    // 0..15 query row (same grouping in all phases)
    const int lr  = tid & 15;    // 0..15 lane-in-row
    const int t   = t0 + qi;
    const int jlo = t - WIN_L;
    const int jhi = t + WIN_R;

    // load Q tile (16 rows x 64) — coalesced, one float4 per thread
    {
        const float* src = qkv + ((size_t)(n * SEQ + t0 + qi) * 3 + 0) * D_MODEL
                           + h * HEAD_DIM + lr * 4;
        *(float4*)&Qs[qi][lr * 4] = *(const float4*)src;
    }

    // ---- scores ----
    for (int c = 0; c < nch; ++c) {
        const int s0 = lo + c * 64;
        const int cw = min(64, hi - s0);
        __syncthreads();   // previous chunk's Kch reads done; also covers Qs store
        {
            const int rr = tid >> 4, f4 = tid & 15;
#pragma unroll
            for (int p = 0; p < 4; ++p) {
                int srow = rr + p * 16;
                if (srow < cw) {
                    const float* src = qkv + ((size_t)(n * SEQ + s0 + srow) * 3 + 1) * D_MODEL
                                       + h * HEAD_DIM + f4 * 4;
                    *(float4*)&Kch[srow][f4 * 4] = *(const float4*)src;
                }
            }
        }
        __syncthreads();
        float a0 = 0.f, a1 = 0.f, a2 = 0.f, a3 = 0.f;
#pragma unroll
        for (int d4 = 0; d4 < 16; ++d4) {
            float4 qv = *(const float4*)&Qs[qi][d4 * 4];
            float4 k0 = *(const float4*)&Kch[lr][d4 * 4];
            float4 k1 = *(const float4*)&Kch[lr + 16][d4 * 4];
            float4 k2 = *(const float4*)&Kch[lr + 32][d4 * 4];
            float4 k3 = *(const float4*)&Kch[lr + 48][d4 * 4];
            a0 = fmaf(qv.x, k0.x, fmaf(qv.y, k0.y, fmaf(qv.z, k0.z, fmaf(qv.w, k0.w, a0))));
            a1 = fmaf(qv.x, k1.x, fmaf(qv.y, k1.y, fmaf(qv.z, k1.z, fmaf(qv.w, k1.w, a1))));
            a2 = fmaf(qv.x, k2.x, fmaf(qv.y, k2.y, fmaf(qv.z, k2.z, fmaf(qv.w, k2.w, a2))));
            a3 = fmaf(qv.x, k3.x, fmaf(qv.y, k3.y, fmaf(qv.z, k3.z, fmaf(qv.w, k3.w, a3))));
        }
        const float scale = 0.125f;
        float av[4] = {a0, a1, a2, a3};
#pragma unroll
        for (int j = 0; j < 4; ++j) {
            int sl = lr + 16 * j;
            int sg = s0 + sl;
            // select, never arithmetic, so garbage LDS rows can't poison (NaN) us
            float val = (sl < cw && sg >= jlo && sg <= jhi) ? av[j] * scale : -INFINITY;
            Sc[qi][c * 64 + sl] = val;
        }
    }
    __syncthreads();

    // ---- softmax (row qi handled by its own 16 lanes; butterfly shuffles) ----
    const int wtot = nch * 64;
    float mx = -INFINITY;
    for (int i = lr; i < wtot; i += 16) mx = fmaxf(mx, Sc[qi][i]);
#pragma unroll
    for (int o = 8; o >= 1; o >>= 1) mx = fmaxf(mx, __shfl_xor(mx, o, 64));
    float sum = 0.f;
    for (int i = lr; i < wtot; i += 16) {
        float pv = __expf(Sc[qi][i] - mx);
        Sc[qi][i] = pv;
        sum += pv;
    }
#pragma unroll
    for (int o = 8; o >= 1; o >>= 1) sum += __shfl_xor(sum, o, 64);
    const float inv = 1.0f / sum;
    __syncthreads();

    // ---- PV ----
    float o0 = 0.f, o1 = 0.f, o2 = 0.f, o3 = 0.f;
    for (int c = 0; c < nch; ++c) {
        const int s0 = lo + c * 64;
        const int cw = min(64, hi - s0);
        __syncthreads();
        {
            const int rr = tid >> 4, f4 = tid & 15;
#pragma unroll
            for (int p = 0; p < 4; ++p) {
                int srow = rr + p * 16;
                if (srow < cw) {
                    const float* src = qkv + ((size_t)(n * SEQ + s0 + srow) * 3 + 2) * D_MODEL
                                       + h * HEAD_DIM + f4 * 4;
                    *(float4*)&Vch[srow][f4 * 4] = *(const float4*)src;
                }
            }
        }
        __syncthreads();
        for (int s = 0; s < cw; ++s) {
            float pv = Sc[qi][c * 64 + s];           // broadcast within row group
            float4 vv = *(const float4*)&Vch[s][lr * 4];
            o0 = fmaf(pv, vv.x, o0);
            o1 = fmaf(pv, vv.y, o1);
            o2 = fmaf(pv, vv.z, o2);
            o3 = fmaf(pv, vv.w, o3);
        }
    }
    float4 outv = make_float4(o0 * inv, o1 * inv, o2 * inv, o3 * inv);
    *(float4*)&attn[(size_t)(n * SEQ + t) * D_MODEL + h * HEAD_DIM + lr * 4] = outv;
}

// ---------------------------------------------------------------------------
extern "C" void kernel_launch(void* const* d_in, const int* in_sizes, int n_in,
                              void* d_out, int out_size, void* d_ws, size_t ws_size,
                              hipStream_t stream)
{
    (void)in_sizes; (void)n_in; (void)out_size; (void)ws_size;
    const float* x     = (const float*)d_in[0];
    const float* w_qkv = (const float*)d_in[1];
    const float* w_out = (const float*)d_in[2];
    const float* b_out = (const float*)d_in[3];
    float* out = (float*)d_out;

    const int M = BATCH * SEQ;                 // 4096
    float* qkv  = (float*)d_ws;                // M * 3072 floats (50.3 MB)
    float* attn = qkv + (size_t)M * 3 * D_MODEL; // M * 1024 floats (16.8 MB)

    dim3 blk(256);

    // 1) qkv = x @ w_qkv^T   (M=4096, N=3072, K=1024)
    sgemm_nt<false><<<dim3(3 * D_MODEL / 128, M / 128), blk, 0, stream>>>(
        x, w_qkv, nullptr, qkv, M, 3 * D_MODEL, D_MODEL);

    // 2) RoPE in place on q,k
    rope_qk<<<dim3(SEQ, BATCH), blk, 0, stream>>>(qkv);

    // 3) banded attention -> attn (n,t,h,d)
    attn_band<<<dim3(SEQ / 16, N_HEADS, BATCH), blk, 0, stream>>>(qkv, attn);

    // 4) out = attn @ w_out^T + b_out   (M=4096, N=1024, K=1024)
    sgemm_nt<true><<<dim3(D_MODEL / 128, M / 128), blk, 0, stream>>>(
        attn, w_out, b_out, out, M, D_MODEL, D_MODEL);
}

// Round 2
// 365.917 us; speedup vs baseline: 1.9584x; 1.9584x over previous
//
#include <hip/hip_runtime.h>
#include <math.h>

#define D_MODEL 1024
#define N_HEADS 16
#define HEAD_DIM 64
#define BATCH 2
#define SEQ 2048
#define WIN_L 127
#define WIN_R 128

typedef float f32x4 __attribute__((ext_vector_type(4)));
typedef __bf16 bf16x8 __attribute__((ext_vector_type(8)));

typedef const __attribute__((address_space(1))) void* gptr_t;
typedef __attribute__((address_space(3))) void* lptr_t;

__device__ __forceinline__ unsigned short f2bf(float v) {
    unsigned u = __float_as_uint(v);
    unsigned r = (u + 0x7FFF + ((u >> 16) & 1)) >> 16;   // RNE
    return (unsigned short)r;
}

// ---------------------------------------------------------------------------
// fp32 -> bf16 elementwise (n must be a multiple of 4)
// ---------------------------------------------------------------------------
__global__ __launch_bounds__(256)
void cvt_f32_bf16(const float* __restrict__ src, unsigned short* __restrict__ dst, int n)
{
    int i = (blockIdx.x * 256 + threadIdx.x) * 4;
    if (i < n) {
        float4 f = *(const float4*)(src + i);
        ushort4 o;
        o.x = f2bf(f.x); o.y = f2bf(f.y); o.z = f2bf(f.z); o.w = f2bf(f.w);
        *(ushort4*)(dst + i) = o;
    }
}

// ---------------------------------------------------------------------------
// bf16 MFMA GEMM (NT): C[m][n] = sum_k A[m][k] * B[n][k] (+ bias[n]), fp32 out.
// A: MxK bf16 row-major, B: NxK bf16 row-major. M,N % 128 == 0, K % 32 == 0.
// m97 structure: 128x128 tile, BK=32, 4 waves each 64x64 as 4x4 of 16x16x32,
// global_load_lds width-16 staging into lane-linear LDS, ds_read_b128 frags.
// ---------------------------------------------------------------------------
template<bool HAS_BIAS>
__global__ __launch_bounds__(256, 2)
void gemm_bt_bf16(const unsigned short* __restrict__ A,
                  const unsigned short* __restrict__ B,
                  const float* __restrict__ bias, float* __restrict__ C,
                  int M, int N, int K)
{
    __shared__ __attribute__((aligned(16))) unsigned short Al[128 * 32];
    __shared__ __attribute__((aligned(16))) unsigned short Bl[128 * 32];

    const int tid  = threadIdx.x;
    const int wave = tid >> 6;
    const int lane = tid & 63;
    const int m0 = blockIdx.y * 128;
    const int n0 = blockIdx.x * 128;

    const int wm = (wave >> 1) * 64;     // wave's row offset in tile
    const int wn = (wave & 1) * 64;      // wave's col offset in tile
    const int quad = lane >> 4;          // 0..3
    const int l16  = lane & 15;

    // staging: one wave-instr covers 16 rows x 32 cols (64 lanes x 16 B)
    const int srow = lane >> 2;          // 0..15
    const int scol = (lane & 3) * 8;     // bf16 element offset within row

    f32x4 acc[4][4] = {};

    for (int k0 = 0; k0 < K; k0 += 32) {
        __syncthreads();                 // previous iter's LDS reads complete
#pragma unroll
        for (int l = 0; l < 2; ++l) {
            const int r = l * 64 + wave * 16 + srow;    // row within tile
            const unsigned short* gA = A + (size_t)(m0 + r) * K + k0 + scol;
            const unsigned short* gB = B + (size_t)(n0 + r) * K + k0 + scol;
            __builtin_amdgcn_global_load_lds((gptr_t)gA, (lptr_t)&Al[r * 32 + scol], 16, 0, 0);
            __builtin_amdgcn_global_load_lds((gptr_t)gB, (lptr_t)&Bl[r * 32 + scol], 16, 0, 0);
        }
        __syncthreads();                 // drains vmcnt -> staging visible

        bf16x8 af[4], bf[4];
#pragma unroll
        for (int i = 0; i < 4; ++i)
            af[i] = *(const bf16x8*)&Al[(wm + i * 16 + l16) * 32 + quad * 8];
#pragma unroll
        for (int j = 0; j < 4; ++j)
            bf[j] = *(const bf16x8*)&Bl[(wn + j * 16 + l16) * 32 + quad * 8];
#pragma unroll
        for (int i = 0; i < 4; ++i)
#pragma unroll
            for (int j = 0; j < 4; ++j)
                acc[i][j] = __builtin_amdgcn_mfma_f32_16x16x32_bf16(af[i], bf[j], acc[i][j], 0, 0, 0);
    }

    // epilogue: C/D layout col = lane&15, row = quad*4 + reg
#pragma unroll
    for (int i = 0; i < 4; ++i) {
        const int row_base = m0 + wm + i * 16 + quad * 4;
#pragma unroll
        for (int j = 0; j < 4; ++j) {
            const int col = n0 + wn + j * 16 + l16;
            const float bv = HAS_BIAS ? bias[col] : 0.0f;
#pragma unroll
            for (int r = 0; r < 4; ++r)
                C[(size_t)(row_base + r) * N + col] = acc[i][j][r] + bv;
        }
    }
}

// ---------------------------------------------------------------------------
// RoPE in-place on q and k slices of qkv[(n,t), 3, H, HD] (fp32).
// ---------------------------------------------------------------------------
__global__ __launch_bounds__(256)
void rope_qk(float* __restrict__ qkv)
{
    const int t = blockIdx.x;
    const int n = blockIdx.y;
    const int tid = threadIdx.x;
#pragma unroll
    for (int idx = tid; idx < 1024; idx += 256) {
        const int which = idx >> 9;       // 0 = q, 1 = k
        const int p = idx & 511;
        const int h = p >> 5;
        const int d = p & 31;
        float invf = powf(10000.0f, -(float)d * (1.0f / 32.0f));
        float ang = (float)t * invf;
        float s, c;
        sincosf(ang, &s, &c);
        float* base = qkv + ((size_t)(n * SEQ + t) * 3 + which) * D_MODEL + h * HEAD_DIM + d;
        float x1 = base[0];
        float x2 = base[32];
        base[0]  = x1 * c - x2 * s;
        base[32] = x2 * c + x1 * s;
    }
}

// ---------------------------------------------------------------------------
// Banded attention (fp32 compute), writes bf16 output for the out-projection.
// Block = (16 queries, one (n,h)). Band union <= 271 keys, 64-key chunks.
// ---------------------------------------------------------------------------
__global__ __launch_bounds__(256)
void attn_band(const float* __restrict__ qkv, unsigned short* __restrict__ attnb)
{
    const int TQ = 16;
    __shared__ float Qs[TQ][64];
    __shared__ float Kch[64][68];
    __shared__ float Vch[64][68];
    __shared__ float Sc[TQ][320];

    const int tid = threadIdx.x;
    const int t0 = blockIdx.x * TQ;
    const int h  = blockIdx.y;
    const int n  = blockIdx.z;

    const int lo = max(0, t0 - WIN_L);
    const int hi = min(SEQ, t0 + TQ - 1 + WIN_R + 1);   // exclusive
    const int nch = (hi - lo + 63) >> 6;

    const int qi  = tid >> 4;    // 0..15 query row
    const int lr  = tid & 15;    // 0..15 lane-in-row
    const int t   = t0 + qi;
    const int jlo = t - WIN_L;
    const int jhi = t + WIN_R;

    {
        const float* src = qkv + ((size_t)(n * SEQ + t0 + qi) * 3 + 0) * D_MODEL
                           + h * HEAD_DIM + lr * 4;
        *(float4*)&Qs[qi][lr * 4] = *(const float4*)src;
    }

    // ---- scores ----
    for (int c = 0; c < nch; ++c) {
        const int s0 = lo + c * 64;
        const int cw = min(64, hi - s0);
        __syncthreads();
        {
            const int rr = tid >> 4, f4 = tid & 15;
#pragma unroll
            for (int p = 0; p < 4; ++p) {
                int srow = rr + p * 16;
                if (srow < cw) {
                    const float* src = qkv + ((size_t)(n * SEQ + s0 + srow) * 3 + 1) * D_MODEL
                                       + h * HEAD_DIM + f4 * 4;
                    *(float4*)&Kch[srow][f4 * 4] = *(const float4*)src;
                }
            }
        }
        __syncthreads();
        float a0 = 0.f, a1 = 0.f, a2 = 0.f, a3 = 0.f;
#pragma unroll
        for (int d4 = 0; d4 < 16; ++d4) {
            float4 qv = *(const float4*)&Qs[qi][d4 * 4];
            float4 k0 = *(const float4*)&Kch[lr][d4 * 4];
            float4 k1 = *(const float4*)&Kch[lr + 16][d4 * 4];
            float4 k2 = *(const float4*)&Kch[lr + 32][d4 * 4];
            float4 k3 = *(const float4*)&Kch[lr + 48][d4 * 4];
            a0 = fmaf(qv.x, k0.x, fmaf(qv.y, k0.y, fmaf(qv.z, k0.z, fmaf(qv.w, k0.w, a0))));
            a1 = fmaf(qv.x, k1.x, fmaf(qv.y, k1.y, fmaf(qv.z, k1.z, fmaf(qv.w, k1.w, a1))));
            a2 = fmaf(qv.x, k2.x, fmaf(qv.y, k2.y, fmaf(qv.z, k2.z, fmaf(qv.w, k2.w, a2))));
            a3 = fmaf(qv.x, k3.x, fmaf(qv.y, k3.y, fmaf(qv.z, k3.z, fmaf(qv.w, k3.w, a3))));
        }
        const float scale = 0.125f;
        float av[4] = {a0, a1, a2, a3};
#pragma unroll
        for (int j = 0; j < 4; ++j) {
            int sl = lr + 16 * j;
            int sg = s0 + sl;
            float val = (sl < cw && sg >= jlo && sg <= jhi) ? av[j] * scale : -INFINITY;
            Sc[qi][c * 64 + sl] = val;
        }
    }
    __syncthreads();

    // ---- softmax ----
    const int wtot = nch * 64;
    float mx = -INFINITY;
    for (int i = lr; i < wtot; i += 16) mx = fmaxf(mx, Sc[qi][i]);
#pragma unroll
    for (int o = 8; o >= 1; o >>= 1) mx = fmaxf(mx, __shfl_xor(mx, o, 64));
    float sum = 0.f;
    for (int i = lr; i < wtot; i += 16) {
        float pv = __expf(Sc[qi][i] - mx);
        Sc[qi][i] = pv;
        sum += pv;
    }
#pragma unroll
    for (int o = 8; o >= 1; o >>= 1) sum += __shfl_xor(sum, o, 64);
    const float inv = 1.0f / sum;
    __syncthreads();

    // ---- PV ----
    float o0 = 0.f, o1 = 0.f, o2 = 0.f, o3 = 0.f;
    for (int c = 0; c < nch; ++c) {
        const int s0 = lo + c * 64;
        const int cw = min(64, hi - s0);
        __syncthreads();
        {
            const int rr = tid >> 4, f4 = tid & 15;
#pragma unroll
            for (int p = 0; p < 4; ++p) {
                int srow = rr + p * 16;
                if (srow < cw) {
                    const float* src = qkv + ((size_t)(n * SEQ + s0 + srow) * 3 + 2) * D_MODEL
                                       + h * HEAD_DIM + f4 * 4;
                    *(float4*)&Vch[srow][f4 * 4] = *(const float4*)src;
                }
            }
        }
        __syncthreads();
        for (int s = 0; s < cw; ++s) {
            float pv = Sc[qi][c * 64 + s];
            float4 vv = *(const float4*)&Vch[s][lr * 4];
            o0 = fmaf(pv, vv.x, o0);
            o1 = fmaf(pv, vv.y, o1);
            o2 = fmaf(pv, vv.z, o2);
            o3 = fmaf(pv, vv.w, o3);
        }
    }
    ushort4 ov;
    ov.x = f2bf(o0 * inv); ov.y = f2bf(o1 * inv);
    ov.z = f2bf(o2 * inv); ov.w = f2bf(o3 * inv);
    *(ushort4*)&attnb[(size_t)(n * SEQ + t) * D_MODEL + h * HEAD_DIM + lr * 4] = ov;
}

// ---------------------------------------------------------------------------
extern "C" void kernel_launch(void* const* d_in, const int* in_sizes, int n_in,
                              void* d_out, int out_size, void* d_ws, size_t ws_size,
                              hipStream_t stream)
{
    (void)in_sizes; (void)n_in; (void)out_size; (void)ws_size;
    const float* x     = (const float*)d_in[0];
    const float* w_qkv = (const float*)d_in[1];
    const float* w_out = (const float*)d_in[2];
    const float* b_out = (const float*)d_in[3];
    float* out = (float*)d_out;

    const int M = BATCH * SEQ;                 // 4096

    // workspace layout (67.11 MB total):
    //   qkv  fp32  M*3072            = 50.33 MB
    //   xb   bf16  M*1024 (reused as attn bf16 output after QKV GEMM)
    //   wqb  bf16  3072*1024
    //   wob  bf16  1024*1024
    float* qkv = (float*)d_ws;
    unsigned short* xb  = (unsigned short*)(qkv + (size_t)M * 3 * D_MODEL);
    unsigned short* wqb = xb  + (size_t)M * D_MODEL;
    unsigned short* wob = wqb + (size_t)3 * D_MODEL * D_MODEL;
    unsigned short* attnb = xb;   // reuse after QKV GEMM consumed xb

    dim3 blk(256);

    // 0) fp32 -> bf16 conversions
    {
        int nx = M * D_MODEL;               // 4.19M
        int nw = 3 * D_MODEL * D_MODEL;     // 3.15M
        int no = D_MODEL * D_MODEL;         // 1.05M
        cvt_f32_bf16<<<dim3((nx / 4 + 255) / 256), blk, 0, stream>>>(x, xb, nx);
        cvt_f32_bf16<<<dim3((nw / 4 + 255) / 256), blk, 0, stream>>>(w_qkv, wqb, nw);
        cvt_f32_bf16<<<dim3((no / 4 + 255) / 256), blk, 0, stream>>>(w_out, wob, no);
    }

    // 1) qkv = x @ w_qkv^T   (M=4096, N=3072, K=1024) -> fp32
    gemm_bt_bf16<false><<<dim3(3 * D_MODEL / 128, M / 128), blk, 0, stream>>>(
        xb, wqb, nullptr, qkv, M, 3 * D_MODEL, D_MODEL);

    // 2) RoPE in place on q,k
    rope_qk<<<dim3(SEQ, BATCH), blk, 0, stream>>>(qkv);

    // 3) banded attention -> attnb (bf16, reuses xb)
    attn_band<<<dim3(SEQ / 16, N_HEADS, BATCH), blk, 0, stream>>>(qkv, attnb);

    // 4) out = attn @ w_out^T + b_out   (M=4096, N=1024, K=1024)
    gemm_bt_bf16<true><<<dim3(D_MODEL / 128, M / 128), blk, 0, stream>>>(
        attnb, wob, b_out, out, M, D_MODEL, D_MODEL);
}

// Round 3
// 200.484 us; speedup vs baseline: 3.5745x; 1.8252x over previous
//
#include <hip/hip_runtime.h>
#include <math.h>

#define D_MODEL 1024
#define N_HEADS 16
#define HEAD_DIM 64
#define BATCH 2
#define SEQ 2048
#define WIN_L 127
#define WIN_R 128

typedef float f32x4 __attribute__((ext_vector_type(4)));
typedef __bf16 bf16x8 __attribute__((ext_vector_type(8)));

typedef const __attribute__((address_space(1))) void* gptr_t;
typedef __attribute__((address_space(3))) void* lptr_t;

__device__ __forceinline__ unsigned short f2bf(float v) {
    unsigned u = __float_as_uint(v);
    unsigned r = (u + 0x7FFF + ((u >> 16) & 1)) >> 16;   // RNE
    return (unsigned short)r;
}
__device__ __forceinline__ float bf2f(unsigned short u) {
    return __uint_as_float((unsigned)u << 16);
}

// ---------------------------------------------------------------------------
// fp32 -> bf16 elementwise (n must be a multiple of 4)
// ---------------------------------------------------------------------------
__global__ __launch_bounds__(256)
void cvt_f32_bf16(const float* __restrict__ src, unsigned short* __restrict__ dst, int n)
{
    int i = (blockIdx.x * 256 + threadIdx.x) * 4;
    if (i < n) {
        float4 f = *(const float4*)(src + i);
        ushort4 o;
        o.x = f2bf(f.x); o.y = f2bf(f.y); o.z = f2bf(f.z); o.w = f2bf(f.w);
        *(ushort4*)(dst + i) = o;
    }
}

// ---------------------------------------------------------------------------
// QKV GEMM (NT) with fused layout epilogue: C = A(4096x1024) * B(3072x1024)^T,
// written as bf16 into qb,kb [n][h][t][64] and vbT [n][h][64][t].
// m97 structure: 128x128 tile, BK=32, 4 waves, 4x4 of mfma 16x16x32 bf16.
// ---------------------------------------------------------------------------
__global__ __launch_bounds__(256, 2)
void gemm_qkv(const unsigned short* __restrict__ A,
              const unsigned short* __restrict__ B,
              unsigned short* __restrict__ qb,
              unsigned short* __restrict__ kb,
              unsigned short* __restrict__ vbT,
              int M, int N, int K)
{
    __shared__ __attribute__((aligned(16))) unsigned short Al[128 * 32];
    __shared__ __attribute__((aligned(16))) unsigned short Bl[128 * 32];

    const int tid  = threadIdx.x;
    const int wave = tid >> 6;
    const int lane = tid & 63;
    const int m0 = blockIdx.y * 128;
    const int n0 = blockIdx.x * 128;

    const int wm = (wave >> 1) * 64;
    const int wn = (wave & 1) * 64;
    const int quad = lane >> 4;
    const int l16  = lane & 15;

    const int srow = lane >> 2;
    const int scol = (lane & 3) * 8;

    f32x4 acc[4][4] = {};

    for (int k0 = 0; k0 < K; k0 += 32) {
        __syncthreads();
#pragma unroll
        for (int l = 0; l < 2; ++l) {
            const int r = l * 64 + wave * 16 + srow;
            const unsigned short* gA = A + (size_t)(m0 + r) * K + k0 + scol;
            const unsigned short* gB = B + (size_t)(n0 + r) * K + k0 + scol;
            __builtin_amdgcn_global_load_lds((gptr_t)gA, (lptr_t)&Al[r * 32 + scol], 16, 0, 0);
            __builtin_amdgcn_global_load_lds((gptr_t)gB, (lptr_t)&Bl[r * 32 + scol], 16, 0, 0);
        }
        __syncthreads();

        bf16x8 af[4], bf[4];
#pragma unroll
        for (int i = 0; i < 4; ++i)
            af[i] = *(const bf16x8*)&Al[(wm + i * 16 + l16) * 32 + quad * 8];
#pragma unroll
        for (int j = 0; j < 4; ++j)
            bf[j] = *(const bf16x8*)&Bl[(wn + j * 16 + l16) * 32 + quad * 8];
#pragma unroll
        for (int i = 0; i < 4; ++i)
#pragma unroll
            for (int j = 0; j < 4; ++j)
                acc[i][j] = __builtin_amdgcn_mfma_f32_16x16x32_bf16(af[i], bf[j], acc[i][j], 0, 0, 0);
    }

    // epilogue: C/D layout col = lane&15, row = quad*4 + reg
    const int which = (n0 >> 10);   // 0=q 1=k 2=v, uniform per block
#pragma unroll
    for (int i = 0; i < 4; ++i) {
        const int row_base = m0 + wm + i * 16 + quad * 4;
        const int nb = row_base >> 11;
        const int tb = row_base & 2047;       // +r stays within 2048 (row_base % 4 == 0)
#pragma unroll
        for (int j = 0; j < 4; ++j) {
            const int gcol = n0 + wn + j * 16 + l16;
            const int h = (gcol >> 6) & 15;
            const int d = gcol & 63;
            if (which == 2) {
                ushort4 pv;
                pv.x = f2bf(acc[i][j][0]); pv.y = f2bf(acc[i][j][1]);
                pv.z = f2bf(acc[i][j][2]); pv.w = f2bf(acc[i][j][3]);
                *(ushort4*)&vbT[(((size_t)nb * 16 + h) * 64 + d) * SEQ + tb] = pv;
            } else {
                unsigned short* dst = (which == 0 ? qb : kb);
#pragma unroll
                for (int r = 0; r < 4; ++r)
                    dst[(((size_t)nb * 16 + h) * SEQ + tb + r) * 64 + d] = f2bf(acc[i][j][r]);
            }
        }
    }
}

// ---------------------------------------------------------------------------
// bf16 MFMA GEMM (NT) with fp32 output + bias (out-projection).
// ---------------------------------------------------------------------------
__global__ __launch_bounds__(256, 2)
void gemm_out(const unsigned short* __restrict__ A,
              const unsigned short* __restrict__ B,
              const float* __restrict__ bias, float* __restrict__ C,
              int M, int N, int K)
{
    __shared__ __attribute__((aligned(16))) unsigned short Al[128 * 32];
    __shared__ __attribute__((aligned(16))) unsigned short Bl[128 * 32];

    const int tid  = threadIdx.x;
    const int wave = tid >> 6;
    const int lane = tid & 63;
    const int m0 = blockIdx.y * 128;
    const int n0 = blockIdx.x * 128;

    const int wm = (wave >> 1) * 64;
    const int wn = (wave & 1) * 64;
    const int quad = lane >> 4;
    const int l16  = lane & 15;

    const int srow = lane >> 2;
    const int scol = (lane & 3) * 8;

    f32x4 acc[4][4] = {};

    for (int k0 = 0; k0 < K; k0 += 32) {
        __syncthreads();
#pragma unroll
        for (int l = 0; l < 2; ++l) {
            const int r = l * 64 + wave * 16 + srow;
            const unsigned short* gA = A + (size_t)(m0 + r) * K + k0 + scol;
            const unsigned short* gB = B + (size_t)(n0 + r) * K + k0 + scol;
            __builtin_amdgcn_global_load_lds((gptr_t)gA, (lptr_t)&Al[r * 32 + scol], 16, 0, 0);
            __builtin_amdgcn_global_load_lds((gptr_t)gB, (lptr_t)&Bl[r * 32 + scol], 16, 0, 0);
        }
        __syncthreads();

        bf16x8 af[4], bf[4];
#pragma unroll
        for (int i = 0; i < 4; ++i)
            af[i] = *(const bf16x8*)&Al[(wm + i * 16 + l16) * 32 + quad * 8];
#pragma unroll
        for (int j = 0; j < 4; ++j)
            bf[j] = *(const bf16x8*)&Bl[(wn + j * 16 + l16) * 32 + quad * 8];
#pragma unroll
        for (int i = 0; i < 4; ++i)
#pragma unroll
            for (int j = 0; j < 4; ++j)
                acc[i][j] = __builtin_amdgcn_mfma_f32_16x16x32_bf16(af[i], bf[j], acc[i][j], 0, 0, 0);
    }

#pragma unroll
    for (int i = 0; i < 4; ++i) {
        const int row_base = m0 + wm + i * 16 + quad * 4;
#pragma unroll
        for (int j = 0; j < 4; ++j) {
            const int col = n0 + wn + j * 16 + l16;
            const float bv = bias[col];
#pragma unroll
            for (int r = 0; r < 4; ++r)
                C[(size_t)(row_base + r) * N + col] = acc[i][j][r] + bv;
        }
    }
}

// ---------------------------------------------------------------------------
// RoPE in-place on bf16 qb,kb [n][h][t][64]: pair (d, d+32), d in [0,32).
// One thread per pair; idx bits: d:5 | t:11 | h:4 | n:1 | buf:1
// ---------------------------------------------------------------------------
__global__ __launch_bounds__(256)
void rope_bf16(unsigned short* __restrict__ qb, unsigned short* __restrict__ kb)
{
    const int idx = blockIdx.x * 256 + threadIdx.x;
    const int d  = idx & 31;
    const int t  = (idx >> 5) & 2047;
    const int h  = (idx >> 16) & 15;
    const int nb = (idx >> 20) & 1;
    const int buf = idx >> 21;
    unsigned short* base = (buf ? kb : qb)
        + (((size_t)(nb * 16 + h)) * SEQ + t) * 64 + d;
    float invf = powf(10000.0f, -(float)d * (1.0f / 32.0f));
    float s, c;
    sincosf((float)t * invf, &s, &c);
    float x1 = bf2f(base[0]);
    float x2 = bf2f(base[32]);
    base[0]  = f2bf(x1 * c - x2 * s);
    base[32] = f2bf(x2 * c + x1 * s);
}

// ---------------------------------------------------------------------------
// Banded MFMA flash attention.
// Block = (n, h, 64 queries), 4 waves x 16 queries, no inter-wave sharing.
// Per wave: band <= 288 keys (klo 32-aligned), scores in regs (18 x f32x4),
// shuffle softmax, P -> per-wave LDS (stride 296), PV from V^T global frags.
// ---------------------------------------------------------------------------
__global__ __launch_bounds__(256)
void attn_mfma(const unsigned short* __restrict__ qb,
               const unsigned short* __restrict__ kb,
               const unsigned short* __restrict__ vbT,
               unsigned short* __restrict__ attnb)
{
    __shared__ unsigned short Pl[4][16][296];   // per-wave 16 x 296 bf16

    const int tid  = threadIdx.x;
    const int w    = tid >> 6;
    const int lane = tid & 63;
    const int quad = lane >> 4;
    const int l16  = lane & 15;

    const int t0 = blockIdx.x * 64;
    const int h  = blockIdx.y;
    const int nB = blockIdx.z;
    const int nh = nB * 16 + h;

    const int tw  = t0 + w * 16;
    const int klo = max(0, tw - WIN_L) & ~31;          // 32-aligned band start
    const int khi = min(SEQ, tw + 16 + WIN_R);          // exclusive
    const int nchunk = (khi - klo + 31) >> 5;           // <= 9
    const int ntile  = nchunk * 2;                      // <= 18

    // Q A-frags: A[m=l16][k=quad*8+j]
    const unsigned short* qrow = qb + ((size_t)nh * SEQ + tw + l16) * 64;
    bf16x8 aq0 = *(const bf16x8*)(qrow + quad * 8);
    bf16x8 aq1 = *(const bf16x8*)(qrow + 32 + quad * 8);

    f32x4 sreg[18];
#pragma unroll
    for (int i = 0; i < 18; ++i) sreg[i] = (f32x4){0.f, 0.f, 0.f, 0.f};

    const unsigned short* kbase = kb + (size_t)nh * SEQ * 64;

    // ---- QK^T + mask ----
#pragma unroll
    for (int i = 0; i < 18; ++i) {
        if (i < ntile) {
            const int s0 = klo + i * 16;
            const int kr = min(s0 + l16, SEQ - 1);
            const unsigned short* krow = kbase + (size_t)kr * 64;
            bf16x8 bk0 = *(const bf16x8*)(krow + quad * 8);
            bf16x8 bk1 = *(const bf16x8*)(krow + 32 + quad * 8);
            f32x4 s = {0.f, 0.f, 0.f, 0.f};
            s = __builtin_amdgcn_mfma_f32_16x16x32_bf16(aq0, bk0, s, 0, 0, 0);
            s = __builtin_amdgcn_mfma_f32_16x16x32_bf16(aq1, bk1, s, 0, 0, 0);
            const int key = s0 + l16;
#pragma unroll
            for (int r = 0; r < 4; ++r) {
                const int t = tw + quad * 4 + r;
                const bool valid = (key < khi) && (key >= t - WIN_L) && (key <= t + WIN_R);
                sreg[i][r] = valid ? s[r] * 0.125f : -INFINITY;
            }
        }
    }

    // ---- softmax over the band (rows quad*4+r, cols spread over l16) ----
    float mx[4] = {-INFINITY, -INFINITY, -INFINITY, -INFINITY};
#pragma unroll
    for (int i = 0; i < 18; ++i)
        if (i < ntile)
#pragma unroll
            for (int r = 0; r < 4; ++r) mx[r] = fmaxf(mx[r], sreg[i][r]);
#pragma unroll
    for (int r = 0; r < 4; ++r)
#pragma unroll
        for (int o = 8; o >= 1; o >>= 1) mx[r] = fmaxf(mx[r], __shfl_xor(mx[r], o, 64));

    float sm[4] = {0.f, 0.f, 0.f, 0.f};
#pragma unroll
    for (int i = 0; i < 18; ++i)
        if (i < ntile) {
#pragma unroll
            for (int r = 0; r < 4; ++r) {
                float p = __expf(sreg[i][r] - mx[r]);
                sm[r] += p;
                Pl[w][quad * 4 + r][i * 16 + l16] = f2bf(p);
            }
        }
#pragma unroll
    for (int r = 0; r < 4; ++r) {
#pragma unroll
        for (int o = 8; o >= 1; o >>= 1) sm[r] += __shfl_xor(sm[r], o, 64);
        sm[r] = 1.0f / sm[r];
    }

    // ---- PV: O[q][d] = sum_key P[q][key] V[key][d], V^T frags from global ----
    f32x4 oacc[4] = {};
    const unsigned short* vbase = vbT + (size_t)nh * 64 * SEQ;
#pragma unroll
    for (int kc = 0; kc < 9; ++kc) {
        if (kc < nchunk) {
            bf16x8 pf = *(const bf16x8*)&Pl[w][l16][kc * 32 + quad * 8];
            const int toff = klo + kc * 32 + quad * 8;
#pragma unroll
            for (int j = 0; j < 4; ++j) {
                bf16x8 vf = *(const bf16x8*)(vbase + (size_t)(j * 16 + l16) * SEQ + toff);
                oacc[j] = __builtin_amdgcn_mfma_f32_16x16x32_bf16(pf, vf, oacc[j], 0, 0, 0);
            }
        }
    }

    // ---- normalize + store: O row = quad*4+r, col = j*16+l16 ----
#pragma unroll
    for (int j = 0; j < 4; ++j)
#pragma unroll
        for (int r = 0; r < 4; ++r) {
            const int t = tw + quad * 4 + r;
            attnb[((size_t)(nB * SEQ + t)) * D_MODEL + h * 64 + j * 16 + l16] =
                f2bf(oacc[j][r] * sm[r]);
        }
}

// ---------------------------------------------------------------------------
extern "C" void kernel_launch(void* const* d_in, const int* in_sizes, int n_in,
                              void* d_out, int out_size, void* d_ws, size_t ws_size,
                              hipStream_t stream)
{
    (void)in_sizes; (void)n_in; (void)out_size; (void)ws_size;
    const float* x     = (const float*)d_in[0];
    const float* w_qkv = (const float*)d_in[1];
    const float* w_out = (const float*)d_in[2];
    const float* b_out = (const float*)d_in[3];
    float* out = (float*)d_out;

    const int M = BATCH * SEQ;                 // 4096

    // ws layout (ushorts), 41.9 MB total:
    //   qb | kb | vbT | wob | xb | wqb      (vbT before wob: tail over-read
    //   lands on finite bf16 weights)       (attnb reuses xb after QKV GEMM)
    unsigned short* qb  = (unsigned short*)d_ws;
    unsigned short* kb  = qb  + (size_t)4194304;
    unsigned short* vbT = kb  + (size_t)4194304;
    unsigned short* wob = vbT + (size_t)4194304;
    unsigned short* xb  = wob + (size_t)1048576;
    unsigned short* wqb = xb  + (size_t)4194304;
    unsigned short* attnb = xb;

    dim3 blk(256);

    // 0) fp32 -> bf16 conversions
    {
        int nx = M * D_MODEL;               // 4.19M
        int nw = 3 * D_MODEL * D_MODEL;     // 3.15M
        int no = D_MODEL * D_MODEL;         // 1.05M
        cvt_f32_bf16<<<dim3((nx / 4 + 255) / 256), blk, 0, stream>>>(x, xb, nx);
        cvt_f32_bf16<<<dim3((nw / 4 + 255) / 256), blk, 0, stream>>>(w_qkv, wqb, nw);
        cvt_f32_bf16<<<dim3((no / 4 + 255) / 256), blk, 0, stream>>>(w_out, wob, no);
    }

    // 1) fused QKV projection -> qb,kb [n,h,t,64], vbT [n,h,64,t] (bf16)
    gemm_qkv<<<dim3(3 * D_MODEL / 128, M / 128), blk, 0, stream>>>(
        xb, wqb, qb, kb, vbT, M, 3 * D_MODEL, D_MODEL);

    // 2) RoPE in place on qb, kb
    rope_bf16<<<dim3((2 * 2 * 16 * 2048 * 32) / 256), blk, 0, stream>>>(qb, kb);

    // 3) banded MFMA attention -> attnb [n,t,D] bf16
    attn_mfma<<<dim3(SEQ / 64, N_HEADS, BATCH), blk, 0, stream>>>(qb, kb, vbT, attnb);

    // 4) out = attn @ w_out^T + b_out
    gemm_out<<<dim3(D_MODEL / 128, M / 128), blk, 0, stream>>>(
        attnb, wob, b_out, out, M, D_MODEL, D_MODEL);
}

// Round 4
// 179.184 us; speedup vs baseline: 3.9994x; 1.1189x over previous
//
#include <hip/hip_runtime.h>
#include <math.h>

#define D_MODEL 1024
#define N_HEADS 16
#define HEAD_DIM 64
#define BATCH 2
#define SEQ 2048
#define WIN_L 127
#define WIN_R 128

typedef float f32x4 __attribute__((ext_vector_type(4)));
typedef __bf16 bf16x8 __attribute__((ext_vector_type(8)));

typedef const __attribute__((address_space(1))) void* gptr_t;
typedef __attribute__((address_space(3))) void* lptr_t;

__device__ __forceinline__ unsigned short f2bf(float v) {
    unsigned u = __float_as_uint(v);
    unsigned r = (u + 0x7FFF + ((u >> 16) & 1)) >> 16;   // RNE
    return (unsigned short)r;
}
__device__ __forceinline__ float bf2f(unsigned short u) {
    return __uint_as_float((unsigned)u << 16);
}

// ---------------------------------------------------------------------------
// fp32 -> bf16 for all three inputs in one launch.
// Ranges (elements): x 4.19M | w_qkv 3.15M | w_out 1.05M, all %4 == 0.
// ---------------------------------------------------------------------------
#define NX_ELEM (4096 * 1024)
#define NW_ELEM (3072 * 1024)
#define NO_ELEM (1024 * 1024)

__global__ __launch_bounds__(256)
void cvt_all(const float* __restrict__ x, const float* __restrict__ wq,
             const float* __restrict__ wo, unsigned short* __restrict__ xb,
             unsigned short* __restrict__ wqb, unsigned short* __restrict__ wob)
{
    int i = (blockIdx.x * 256 + threadIdx.x) * 4;
    const float* src;
    unsigned short* dst;
    int off;
    if (i < NX_ELEM)                 { src = x;  dst = xb;  off = i; }
    else if (i < NX_ELEM + NW_ELEM)  { src = wq; dst = wqb; off = i - NX_ELEM; }
    else                             { src = wo; dst = wob; off = i - NX_ELEM - NW_ELEM; }
    float4 f = *(const float4*)(src + off);
    ushort4 o;
    o.x = f2bf(f.x); o.y = f2bf(f.y); o.z = f2bf(f.z); o.w = f2bf(f.w);
    *(ushort4*)(dst + off) = o;
}

// ---------------------------------------------------------------------------
// QKV GEMM (NT) with fused RoPE + layout epilogue.
// C = A(4096x1024) * B(3072x1024)^T; q,k get RoPE'd in-register (fp32), then
// written bf16 into qb,kb [n][h][t][64]; v written transposed vbT [n][h][64][t].
// m97 structure: 128x128 tile, BK=32, 4 waves, 4x4 of mfma 16x16x32 bf16.
// Each wave's 64 cols = one head, so RoPE pair (d, d+32) = acc[i][j]/acc[i][j+2].
// ---------------------------------------------------------------------------
__global__ __launch_bounds__(256, 2)
void gemm_qkv(const unsigned short* __restrict__ A,
              const unsigned short* __restrict__ B,
              unsigned short* __restrict__ qb,
              unsigned short* __restrict__ kb,
              unsigned short* __restrict__ vbT,
              int M, int N, int K)
{
    __shared__ __attribute__((aligned(16))) unsigned short Al[128 * 32];
    __shared__ __attribute__((aligned(16))) unsigned short Bl[128 * 32];

    const int tid  = threadIdx.x;
    const int wave = tid >> 6;
    const int lane = tid & 63;
    const int m0 = blockIdx.y * 128;
    const int n0 = blockIdx.x * 128;

    const int wm = (wave >> 1) * 64;
    const int wn = (wave & 1) * 64;
    const int quad = lane >> 4;
    const int l16  = lane & 15;

    const int srow = lane >> 2;
    const int scol = (lane & 3) * 8;

    f32x4 acc[4][4] = {};

    for (int k0 = 0; k0 < K; k0 += 32) {
        __syncthreads();
#pragma unroll
        for (int l = 0; l < 2; ++l) {
            const int r = l * 64 + wave * 16 + srow;
            const unsigned short* gA = A + (size_t)(m0 + r) * K + k0 + scol;
            const unsigned short* gB = B + (size_t)(n0 + r) * K + k0 + scol;
            __builtin_amdgcn_global_load_lds((gptr_t)gA, (lptr_t)&Al[r * 32 + scol], 16, 0, 0);
            __builtin_amdgcn_global_load_lds((gptr_t)gB, (lptr_t)&Bl[r * 32 + scol], 16, 0, 0);
        }
        __syncthreads();

        bf16x8 af[4], bf[4];
#pragma unroll
        for (int i = 0; i < 4; ++i)
            af[i] = *(const bf16x8*)&Al[(wm + i * 16 + l16) * 32 + quad * 8];
#pragma unroll
        for (int j = 0; j < 4; ++j)
            bf[j] = *(const bf16x8*)&Bl[(wn + j * 16 + l16) * 32 + quad * 8];
#pragma unroll
        for (int i = 0; i < 4; ++i)
#pragma unroll
            for (int j = 0; j < 4; ++j)
                acc[i][j] = __builtin_amdgcn_mfma_f32_16x16x32_bf16(af[i], bf[j], acc[i][j], 0, 0, 0);
    }

    // epilogue: C/D layout col = lane&15, row = quad*4 + reg
    const int which = (n0 >> 10);   // 0=q 1=k 2=v, uniform per block

    if (which != 2) {
        // ---- fused RoPE (fp32, in-register) ----
        // d = jp*16 + l16 (jp=0,1); partner d+32 lives in acc[i][jp+2].
        // invf = 10000^(-d/32) = 2^(-d * log2(1e4)/32)
        float invf[2];
#pragma unroll
        for (int jp = 0; jp < 2; ++jp)
            invf[jp] = exp2f(-(float)(jp * 16 + l16) * 0.41524101186092f);
#pragma unroll
        for (int i = 0; i < 4; ++i) {
            const int row_base = m0 + wm + i * 16 + quad * 4;
            const int tb = row_base & 2047;
#pragma unroll
            for (int jp = 0; jp < 2; ++jp)
#pragma unroll
                for (int r = 0; r < 4; ++r) {
                    float s, c;
                    __sincosf((float)(tb + r) * invf[jp], &s, &c);
                    float x1 = acc[i][jp][r], x2 = acc[i][jp + 2][r];
                    acc[i][jp][r]     = x1 * c - x2 * s;
                    acc[i][jp + 2][r] = x2 * c + x1 * s;
                }
        }
        unsigned short* dst = (which == 0 ? qb : kb);
#pragma unroll
        for (int i = 0; i < 4; ++i) {
            const int row_base = m0 + wm + i * 16 + quad * 4;
            const int nb = row_base >> 11;
            const int tb = row_base & 2047;
#pragma unroll
            for (int j = 0; j < 4; ++j) {
                const int gcol = n0 + wn + j * 16 + l16;
                const int h = (gcol >> 6) & 15;
                const int d = gcol & 63;
#pragma unroll
                for (int r = 0; r < 4; ++r)
                    dst[(((size_t)nb * 16 + h) * SEQ + tb + r) * 64 + d] = f2bf(acc[i][j][r]);
            }
        }
    } else {
#pragma unroll
        for (int i = 0; i < 4; ++i) {
            const int row_base = m0 + wm + i * 16 + quad * 4;
            const int nb = row_base >> 11;
            const int tb = row_base & 2047;
#pragma unroll
            for (int j = 0; j < 4; ++j) {
                const int gcol = n0 + wn + j * 16 + l16;
                const int h = (gcol >> 6) & 15;
                const int d = gcol & 63;
                ushort4 pv;
                pv.x = f2bf(acc[i][j][0]); pv.y = f2bf(acc[i][j][1]);
                pv.z = f2bf(acc[i][j][2]); pv.w = f2bf(acc[i][j][3]);
                *(ushort4*)&vbT[(((size_t)nb * 16 + h) * 64 + d) * SEQ + tb] = pv;
            }
        }
    }
}

// ---------------------------------------------------------------------------
// bf16 MFMA GEMM (NT) with fp32 output + bias (out-projection).
// ---------------------------------------------------------------------------
__global__ __launch_bounds__(256, 2)
void gemm_out(const unsigned short* __restrict__ A,
              const unsigned short* __restrict__ B,
              const float* __restrict__ bias, float* __restrict__ C,
              int M, int N, int K)
{
    __shared__ __attribute__((aligned(16))) unsigned short Al[128 * 32];
    __shared__ __attribute__((aligned(16))) unsigned short Bl[128 * 32];

    const int tid  = threadIdx.x;
    const int wave = tid >> 6;
    const int lane = tid & 63;
    const int m0 = blockIdx.y * 128;
    const int n0 = blockIdx.x * 128;

    const int wm = (wave >> 1) * 64;
    const int wn = (wave & 1) * 64;
    const int quad = lane >> 4;
    const int l16  = lane & 15;

    const int srow = lane >> 2;
    const int scol = (lane & 3) * 8;

    f32x4 acc[4][4] = {};

    for (int k0 = 0; k0 < K; k0 += 32) {
        __syncthreads();
#pragma unroll
        for (int l = 0; l < 2; ++l) {
            const int r = l * 64 + wave * 16 + srow;
            const unsigned short* gA = A + (size_t)(m0 + r) * K + k0 + scol;
            const unsigned short* gB = B + (size_t)(n0 + r) * K + k0 + scol;
            __builtin_amdgcn_global_load_lds((gptr_t)gA, (lptr_t)&Al[r * 32 + scol], 16, 0, 0);
            __builtin_amdgcn_global_load_lds((gptr_t)gB, (lptr_t)&Bl[r * 32 + scol], 16, 0, 0);
        }
        __syncthreads();

        bf16x8 af[4], bf[4];
#pragma unroll
        for (int i = 0; i < 4; ++i)
            af[i] = *(const bf16x8*)&Al[(wm + i * 16 + l16) * 32 + quad * 8];
#pragma unroll
        for (int j = 0; j < 4; ++j)
            bf[j] = *(const bf16x8*)&Bl[(wn + j * 16 + l16) * 32 + quad * 8];
#pragma unroll
        for (int i = 0; i < 4; ++i)
#pragma unroll
            for (int j = 0; j < 4; ++j)
                acc[i][j] = __builtin_amdgcn_mfma_f32_16x16x32_bf16(af[i], bf[j], acc[i][j], 0, 0, 0);
    }

#pragma unroll
    for (int i = 0; i < 4; ++i) {
        const int row_base = m0 + wm + i * 16 + quad * 4;
#pragma unroll
        for (int j = 0; j < 4; ++j) {
            const int col = n0 + wn + j * 16 + l16;
            const float bv = bias[col];
#pragma unroll
            for (int r = 0; r < 4; ++r)
                C[(size_t)(row_base + r) * N + col] = acc[i][j][r] + bv;
        }
    }
}

// ---------------------------------------------------------------------------
// Banded MFMA flash attention.
// Block = (n, h, 64 queries), 4 waves x 16 queries, no inter-wave sharing.
// Per wave: band <= 288 keys (klo 32-aligned), scores in regs (18 x f32x4),
// shuffle softmax, P -> per-wave LDS (stride 296), PV from V^T global frags.
// ---------------------------------------------------------------------------
__global__ __launch_bounds__(256)
void attn_mfma(const unsigned short* __restrict__ qb,
               const unsigned short* __restrict__ kb,
               const unsigned short* __restrict__ vbT,
               unsigned short* __restrict__ attnb)
{
    __shared__ unsigned short Pl[4][16][296];   // per-wave 16 x 296 bf16

    const int tid  = threadIdx.x;
    const int w    = tid >> 6;
    const int lane = tid & 63;
    const int quad = lane >> 4;
    const int l16  = lane & 15;

    const int t0 = blockIdx.x * 64;
    const int h  = blockIdx.y;
    const int nB = blockIdx.z;
    const int nh = nB * 16 + h;

    const int tw  = t0 + w * 16;
    const int klo = max(0, tw - WIN_L) & ~31;          // 32-aligned band start
    const int khi = min(SEQ, tw + 16 + WIN_R);          // exclusive
    const int nchunk = (khi - klo + 31) >> 5;           // <= 9
    const int ntile  = nchunk * 2;                      // <= 18

    // Q A-frags: A[m=l16][k=quad*8+j]
    const unsigned short* qrow = qb + ((size_t)nh * SEQ + tw + l16) * 64;
    bf16x8 aq0 = *(const bf16x8*)(qrow + quad * 8);
    bf16x8 aq1 = *(const bf16x8*)(qrow + 32 + quad * 8);

    f32x4 sreg[18];
#pragma unroll
    for (int i = 0; i < 18; ++i) sreg[i] = (f32x4){0.f, 0.f, 0.f, 0.f};

    const unsigned short* kbase = kb + (size_t)nh * SEQ * 64;

    // ---- QK^T + mask ----
#pragma unroll
    for (int i = 0; i < 18; ++i) {
        if (i < ntile) {
            const int s0 = klo + i * 16;
            const int kr = min(s0 + l16, SEQ - 1);
            const unsigned short* krow = kbase + (size_t)kr * 64;
            bf16x8 bk0 = *(const bf16x8*)(krow + quad * 8);
            bf16x8 bk1 = *(const bf16x8*)(krow + 32 + quad * 8);
            f32x4 s = {0.f, 0.f, 0.f, 0.f};
            s = __builtin_amdgcn_mfma_f32_16x16x32_bf16(aq0, bk0, s, 0, 0, 0);
            s = __builtin_amdgcn_mfma_f32_16x16x32_bf16(aq1, bk1, s, 0, 0, 0);
            const int key = s0 + l16;
#pragma unroll
            for (int r = 0; r < 4; ++r) {
                const int t = tw + quad * 4 + r;
                const bool valid = (key < khi) && (key >= t - WIN_L) && (key <= t + WIN_R);
                sreg[i][r] = valid ? s[r] * 0.125f : -INFINITY;
            }
        }
    }

    // ---- softmax over the band (rows quad*4+r, cols spread over l16) ----
    float mx[4] = {-INFINITY, -INFINITY, -INFINITY, -INFINITY};
#pragma unroll
    for (int i = 0; i < 18; ++i)
        if (i < ntile)
#pragma unroll
            for (int r = 0; r < 4; ++r) mx[r] = fmaxf(mx[r], sreg[i][r]);
#pragma unroll
    for (int r = 0; r < 4; ++r)
#pragma unroll
        for (int o = 8; o >= 1; o >>= 1) mx[r] = fmaxf(mx[r], __shfl_xor(mx[r], o, 64));

    float sm[4] = {0.f, 0.f, 0.f, 0.f};
#pragma unroll
    for (int i = 0; i < 18; ++i)
        if (i < ntile) {
#pragma unroll
            for (int r = 0; r < 4; ++r) {
                float p = __expf(sreg[i][r] - mx[r]);
                sm[r] += p;
                Pl[w][quad * 4 + r][i * 16 + l16] = f2bf(p);
            }
        }
#pragma unroll
    for (int r = 0; r < 4; ++r) {
#pragma unroll
        for (int o = 8; o >= 1; o >>= 1) sm[r] += __shfl_xor(sm[r], o, 64);
        sm[r] = 1.0f / sm[r];
    }

    // ---- PV: O[q][d] = sum_key P[q][key] V[key][d], V^T frags from global ----
    f32x4 oacc[4] = {};
    const unsigned short* vbase = vbT + (size_t)nh * 64 * SEQ;
#pragma unroll
    for (int kc = 0; kc < 9; ++kc) {
        if (kc < nchunk) {
            bf16x8 pf = *(const bf16x8*)&Pl[w][l16][kc * 32 + quad * 8];
            const int toff = klo + kc * 32 + quad * 8;
#pragma unroll
            for (int j = 0; j < 4; ++j) {
                bf16x8 vf = *(const bf16x8*)(vbase + (size_t)(j * 16 + l16) * SEQ + toff);
                oacc[j] = __builtin_amdgcn_mfma_f32_16x16x32_bf16(pf, vf, oacc[j], 0, 0, 0);
            }
        }
    }

    // ---- normalize + store: O row = quad*4+r, col = j*16+l16 ----
#pragma unroll
    for (int j = 0; j < 4; ++j)
#pragma unroll
        for (int r = 0; r < 4; ++r) {
            const int t = tw + quad * 4 + r;
            attnb[((size_t)(nB * SEQ + t)) * D_MODEL + h * 64 + j * 16 + l16] =
                f2bf(oacc[j][r] * sm[r]);
        }
}

// ---------------------------------------------------------------------------
extern "C" void kernel_launch(void* const* d_in, const int* in_sizes, int n_in,
                              void* d_out, int out_size, void* d_ws, size_t ws_size,
                              hipStream_t stream)
{
    (void)in_sizes; (void)n_in; (void)out_size; (void)ws_size;
    const float* x     = (const float*)d_in[0];
    const float* w_qkv = (const float*)d_in[1];
    const float* w_out = (const float*)d_in[2];
    const float* b_out = (const float*)d_in[3];
    float* out = (float*)d_out;

    const int M = BATCH * SEQ;                 // 4096

    // ws layout (ushorts), 41.9 MB total:
    //   qb | kb | vbT | wob | xb | wqb      (vbT before wob: tail over-read
    //   lands on finite bf16 weights)       (attnb reuses xb after QKV GEMM)
    unsigned short* qb  = (unsigned short*)d_ws;
    unsigned short* kb  = qb  + (size_t)4194304;
    unsigned short* vbT = kb  + (size_t)4194304;
    unsigned short* wob = vbT + (size_t)4194304;
    unsigned short* xb  = wob + (size_t)1048576;
    unsigned short* wqb = xb  + (size_t)4194304;
    unsigned short* attnb = xb;

    dim3 blk(256);

    // 0) fp32 -> bf16 conversions (single launch)
    cvt_all<<<dim3((NX_ELEM + NW_ELEM + NO_ELEM) / 4 / 256), blk, 0, stream>>>(
        x, w_qkv, w_out, xb, wqb, wob);

    // 1) fused QKV projection + RoPE -> qb,kb [n,h,t,64], vbT [n,h,64,t] (bf16)
    gemm_qkv<<<dim3(3 * D_MODEL / 128, M / 128), blk, 0, stream>>>(
        xb, wqb, qb, kb, vbT, M, 3 * D_MODEL, D_MODEL);

    // 2) banded MFMA attention -> attnb [n,t,D] bf16
    attn_mfma<<<dim3(SEQ / 64, N_HEADS, BATCH), blk, 0, stream>>>(qb, kb, vbT, attnb);

    // 3) out = attn @ w_out^T + b_out
    gemm_out<<<dim3(D_MODEL / 128, M / 128), blk, 0, stream>>>(
        attnb, wob, b_out, out, M, D_MODEL, D_MODEL);
}

// Round 5
// 176.767 us; speedup vs baseline: 4.0541x; 1.0137x over previous
//
#include <hip/hip_runtime.h>
#include <math.h>

#define D_MODEL 1024
#define N_HEADS 16
#define HEAD_DIM 64
#define BATCH 2
#define SEQ 2048
#define WIN_L 127
#define WIN_R 128

typedef float f32x4 __attribute__((ext_vector_type(4)));
typedef __bf16 bf16x8 __attribute__((ext_vector_type(8)));
typedef unsigned short ushort8_t __attribute__((ext_vector_type(8)));

typedef const __attribute__((address_space(1))) void* gptr_t;
typedef __attribute__((address_space(3))) void* lptr_t;

__device__ __forceinline__ unsigned short f2bf(float v) {
    unsigned u = __float_as_uint(v);
    unsigned r = (u + 0x7FFF + ((u >> 16) & 1)) >> 16;   // RNE
    return (unsigned short)r;
}
__device__ __forceinline__ float bf2f(unsigned short u) {
    return __uint_as_float((unsigned)u << 16);
}

// ---------------------------------------------------------------------------
// fp32 -> bf16 for all three inputs in one launch.
// ---------------------------------------------------------------------------
#define NX_ELEM (4096 * 1024)
#define NW_ELEM (3072 * 1024)
#define NO_ELEM (1024 * 1024)

__global__ __launch_bounds__(256)
void cvt_all(const float* __restrict__ x, const float* __restrict__ wq,
             const float* __restrict__ wo, unsigned short* __restrict__ xb,
             unsigned short* __restrict__ wqb, unsigned short* __restrict__ wob)
{
    int i = (blockIdx.x * 256 + threadIdx.x) * 4;
    const float* src;
    unsigned short* dst;
    int off;
    if (i < NX_ELEM)                 { src = x;  dst = xb;  off = i; }
    else if (i < NX_ELEM + NW_ELEM)  { src = wq; dst = wqb; off = i - NX_ELEM; }
    else                             { src = wo; dst = wob; off = i - NX_ELEM - NW_ELEM; }
    float4 f = *(const float4*)(src + off);
    ushort4 o;
    o.x = f2bf(f.x); o.y = f2bf(f.y); o.z = f2bf(f.z); o.w = f2bf(f.w);
    *(ushort4*)(dst + off) = o;
}

// ---------------------------------------------------------------------------
// QKV GEMM (NT) with fused RoPE + layout epilogue, coalesced via per-wave LDS
// transpose. q,k RoPE'd in-register (fp32) then stored bf16 [n][h][t][64];
// v stored transposed vbT [n][h][64][t].
// K-loop: m97 structure, 128x128 tile, BK=32, 4 waves, 4x4 mfma 16x16x32.
// Epilogue: wave tile = 64 t-rows x 64 d-cols (one head) -> Tl[wave] (stride
// 68: ds_write_u16 conflict-free, quads 8 banks apart) -> 8x 16B coalesced
// global stores. No barrier: Tl is per-wave private.
// ---------------------------------------------------------------------------
__global__ __launch_bounds__(256, 2)
void gemm_qkv(const unsigned short* __restrict__ A,
              const unsigned short* __restrict__ B,
              unsigned short* __restrict__ qb,
              unsigned short* __restrict__ kb,
              unsigned short* __restrict__ vbT,
              int M, int N, int K)
{
    __shared__ __attribute__((aligned(16))) unsigned short Al[128 * 32];
    __shared__ __attribute__((aligned(16))) unsigned short Bl[128 * 32];
    __shared__ __attribute__((aligned(16))) unsigned short Tl[4][64 * 68];

    const int tid  = threadIdx.x;
    const int wave = tid >> 6;
    const int lane = tid & 63;
    const int m0 = blockIdx.y * 128;
    const int n0 = blockIdx.x * 128;

    const int wm = (wave >> 1) * 64;
    const int wn = (wave & 1) * 64;
    const int quad = lane >> 4;
    const int l16  = lane & 15;

    const int srow = lane >> 2;
    const int scol = (lane & 3) * 8;

    f32x4 acc[4][4] = {};

    for (int k0 = 0; k0 < K; k0 += 32) {
        __syncthreads();
#pragma unroll
        for (int l = 0; l < 2; ++l) {
            const int r = l * 64 + wave * 16 + srow;
            const unsigned short* gA = A + (size_t)(m0 + r) * K + k0 + scol;
            const unsigned short* gB = B + (size_t)(n0 + r) * K + k0 + scol;
            __builtin_amdgcn_global_load_lds((gptr_t)gA, (lptr_t)&Al[r * 32 + scol], 16, 0, 0);
            __builtin_amdgcn_global_load_lds((gptr_t)gB, (lptr_t)&Bl[r * 32 + scol], 16, 0, 0);
        }
        __syncthreads();

        bf16x8 af[4], bf[4];
#pragma unroll
        for (int i = 0; i < 4; ++i)
            af[i] = *(const bf16x8*)&Al[(wm + i * 16 + l16) * 32 + quad * 8];
#pragma unroll
        for (int j = 0; j < 4; ++j)
            bf[j] = *(const bf16x8*)&Bl[(wn + j * 16 + l16) * 32 + quad * 8];
#pragma unroll
        for (int i = 0; i < 4; ++i)
#pragma unroll
            for (int j = 0; j < 4; ++j)
                acc[i][j] = __builtin_amdgcn_mfma_f32_16x16x32_bf16(af[i], bf[j], acc[i][j], 0, 0, 0);
    }

    // ---- epilogue ----
    // C/D layout: col(d) = l16 + j*16, row(t) = quad*4 + r + i*16.
    const int which = (n0 >> 10);   // 0=q 1=k 2=v, uniform per block
    unsigned short* Tw = &Tl[wave][0];

    if (which != 2) {
        // fused RoPE (fp32, in-register): d = jp*16+l16, partner acc[i][jp+2]
        float invf[2];
#pragma unroll
        for (int jp = 0; jp < 2; ++jp)
            invf[jp] = exp2f(-(float)(jp * 16 + l16) * 0.41524101186092f);
#pragma unroll
        for (int i = 0; i < 4; ++i) {
            const int tb = (m0 + wm + i * 16 + quad * 4) & 2047;
#pragma unroll
            for (int jp = 0; jp < 2; ++jp)
#pragma unroll
                for (int r = 0; r < 4; ++r) {
                    float s, c;
                    __sincosf((float)(tb + r) * invf[jp], &s, &c);
                    float x1 = acc[i][jp][r], x2 = acc[i][jp + 2][r];
                    acc[i][jp][r]     = x1 * c - x2 * s;
                    acc[i][jp + 2][r] = x2 * c + x1 * s;
                }
        }
        // Tw[t_loc][d], t_loc = i*16+quad*4+r, d = j*16+l16
#pragma unroll
        for (int i = 0; i < 4; ++i)
#pragma unroll
            for (int j = 0; j < 4; ++j)
#pragma unroll
                for (int r = 0; r < 4; ++r)
                    Tw[(i * 16 + quad * 4 + r) * 68 + j * 16 + l16] = f2bf(acc[i][j][r]);
    } else {
        // Tw[d][t_loc], d = j*16+l16, t_loc = i*16+quad*4+r (r contiguous)
#pragma unroll
        for (int i = 0; i < 4; ++i)
#pragma unroll
            for (int j = 0; j < 4; ++j) {
                ushort4 pv;
                pv.x = f2bf(acc[i][j][0]); pv.y = f2bf(acc[i][j][1]);
                pv.z = f2bf(acc[i][j][2]); pv.w = f2bf(acc[i][j][3]);
                *(ushort4*)&Tw[(j * 16 + l16) * 68 + i * 16 + quad * 4] = pv;
            }
    }

    // coalesced store phase (per-wave; compiler inserts lgkmcnt waits)
    {
        const int h   = ((n0 + wn) >> 6) & 15;
        const int nb  = (m0 + wm) >> 11;
        const int tw0 = (m0 + wm) & 2047;
        const int lr8 = lane >> 3;          // 0..7
        const int lc8 = (lane & 7) * 8;     // element offset in row
        if (which != 2) {
            unsigned short* dst = (which == 0 ? qb : kb);
            unsigned short* gb = dst + (((size_t)nb * 16 + h) * SEQ + tw0) * 64;
#pragma unroll
            for (int c = 0; c < 8; ++c) {
                const int row = c * 8 + lr8;
                ushort4 lo = *(const ushort4*)&Tw[row * 68 + lc8];
                ushort4 hi = *(const ushort4*)&Tw[row * 68 + lc8 + 4];
                ushort8_t v8 = {lo.x, lo.y, lo.z, lo.w, hi.x, hi.y, hi.z, hi.w};
                *(ushort8_t*)&gb[row * 64 + lc8] = v8;   // lane-contiguous 1 KB
            }
        } else {
            unsigned short* gb = vbT + ((size_t)nb * 16 + h) * 64 * SEQ + tw0;
#pragma unroll
            for (int c = 0; c < 8; ++c) {
                const int drow = c * 8 + lr8;
                ushort4 lo = *(const ushort4*)&Tw[drow * 68 + lc8];
                ushort4 hi = *(const ushort4*)&Tw[drow * 68 + lc8 + 4];
                ushort8_t v8 = {lo.x, lo.y, lo.z, lo.w, hi.x, hi.y, hi.z, hi.w};
                *(ushort8_t*)&gb[(size_t)drow * SEQ + lc8] = v8;  // 128B rows
            }
        }
    }
}

// ---------------------------------------------------------------------------
// bf16 MFMA GEMM (NT) with fp32 output + bias (out-projection).
// ---------------------------------------------------------------------------
__global__ __launch_bounds__(256, 2)
void gemm_out(const unsigned short* __restrict__ A,
              const unsigned short* __restrict__ B,
              const float* __restrict__ bias, float* __restrict__ C,
              int M, int N, int K)
{
    __shared__ __attribute__((aligned(16))) unsigned short Al[128 * 32];
    __shared__ __attribute__((aligned(16))) unsigned short Bl[128 * 32];

    const int tid  = threadIdx.x;
    const int wave = tid >> 6;
    const int lane = tid & 63;
    const int m0 = blockIdx.y * 128;
    const int n0 = blockIdx.x * 128;

    const int wm = (wave >> 1) * 64;
    const int wn = (wave & 1) * 64;
    const int quad = lane >> 4;
    const int l16  = lane & 15;

    const int srow = lane >> 2;
    const int scol = (lane & 3) * 8;

    f32x4 acc[4][4] = {};

    for (int k0 = 0; k0 < K; k0 += 32) {
        __syncthreads();
#pragma unroll
        for (int l = 0; l < 2; ++l) {
            const int r = l * 64 + wave * 16 + srow;
            const unsigned short* gA = A + (size_t)(m0 + r) * K + k0 + scol;
            const unsigned short* gB = B + (size_t)(n0 + r) * K + k0 + scol;
            __builtin_amdgcn_global_load_lds((gptr_t)gA, (lptr_t)&Al[r * 32 + scol], 16, 0, 0);
            __builtin_amdgcn_global_load_lds((gptr_t)gB, (lptr_t)&Bl[r * 32 + scol], 16, 0, 0);
        }
        __syncthreads();

        bf16x8 af[4], bf[4];
#pragma unroll
        for (int i = 0; i < 4; ++i)
            af[i] = *(const bf16x8*)&Al[(wm + i * 16 + l16) * 32 + quad * 8];
#pragma unroll
        for (int j = 0; j < 4; ++j)
            bf[j] = *(const bf16x8*)&Bl[(wn + j * 16 + l16) * 32 + quad * 8];
#pragma unroll
        for (int i = 0; i < 4; ++i)
#pragma unroll
            for (int j = 0; j < 4; ++j)
                acc[i][j] = __builtin_amdgcn_mfma_f32_16x16x32_bf16(af[i], bf[j], acc[i][j], 0, 0, 0);
    }

#pragma unroll
    for (int i = 0; i < 4; ++i) {
        const int row_base = m0 + wm + i * 16 + quad * 4;
#pragma unroll
        for (int j = 0; j < 4; ++j) {
            const int col = n0 + wn + j * 16 + l16;
            const float bv = bias[col];
#pragma unroll
            for (int r = 0; r < 4; ++r)
                C[(size_t)(row_base + r) * N + col] = acc[i][j][r] + bv;
        }
    }
}

// ---------------------------------------------------------------------------
// Banded MFMA flash attention.
// Block = (n, h, 64 queries), 4 waves x 16 queries, no inter-wave sharing.
// ---------------------------------------------------------------------------
__global__ __launch_bounds__(256, 4)
void attn_mfma(const unsigned short* __restrict__ qb,
               const unsigned short* __restrict__ kb,
               const unsigned short* __restrict__ vbT,
               unsigned short* __restrict__ attnb)
{
    __shared__ unsigned short Pl[4][16][296];   // per-wave 16 x 296 bf16

    const int tid  = threadIdx.x;
    const int w    = tid >> 6;
    const int lane = tid & 63;
    const int quad = lane >> 4;
    const int l16  = lane & 15;

    const int t0 = blockIdx.x * 64;
    const int h  = blockIdx.y;
    const int nB = blockIdx.z;
    const int nh = nB * 16 + h;

    const int tw  = t0 + w * 16;
    const int klo = max(0, tw - WIN_L) & ~31;          // 32-aligned band start
    const int khi = min(SEQ, tw + 16 + WIN_R);          // exclusive
    const int nchunk = (khi - klo + 31) >> 5;           // <= 9
    const int ntile  = nchunk * 2;                      // <= 18

    const unsigned short* qrow = qb + ((size_t)nh * SEQ + tw + l16) * 64;
    bf16x8 aq0 = *(const bf16x8*)(qrow + quad * 8);
    bf16x8 aq1 = *(const bf16x8*)(qrow + 32 + quad * 8);

    f32x4 sreg[18];
#pragma unroll
    for (int i = 0; i < 18; ++i) sreg[i] = (f32x4){0.f, 0.f, 0.f, 0.f};

    const unsigned short* kbase = kb + (size_t)nh * SEQ * 64;

    // ---- QK^T + mask ----
#pragma unroll
    for (int i = 0; i < 18; ++i) {
        if (i < ntile) {
            const int s0 = klo + i * 16;
            const int kr = min(s0 + l16, SEQ - 1);
            const unsigned short* krow = kbase + (size_t)kr * 64;
            bf16x8 bk0 = *(const bf16x8*)(krow + quad * 8);
            bf16x8 bk1 = *(const bf16x8*)(krow + 32 + quad * 8);
            f32x4 s = {0.f, 0.f, 0.f, 0.f};
            s = __builtin_amdgcn_mfma_f32_16x16x32_bf16(aq0, bk0, s, 0, 0, 0);
            s = __builtin_amdgcn_mfma_f32_16x16x32_bf16(aq1, bk1, s, 0, 0, 0);
            const int key = s0 + l16;
#pragma unroll
            for (int r = 0; r < 4; ++r) {
                const int t = tw + quad * 4 + r;
                const bool valid = (key < khi) && (key >= t - WIN_L) && (key <= t + WIN_R);
                sreg[i][r] = valid ? s[r] * 0.125f : -INFINITY;
            }
        }
    }

    // ---- softmax ----
    float mx[4] = {-INFINITY, -INFINITY, -INFINITY, -INFINITY};
#pragma unroll
    for (int i = 0; i < 18; ++i)
        if (i < ntile)
#pragma unroll
            for (int r = 0; r < 4; ++r) mx[r] = fmaxf(mx[r], sreg[i][r]);
#pragma unroll
    for (int r = 0; r < 4; ++r)
#pragma unroll
        for (int o = 8; o >= 1; o >>= 1) mx[r] = fmaxf(mx[r], __shfl_xor(mx[r], o, 64));

    float sm[4] = {0.f, 0.f, 0.f, 0.f};
#pragma unroll
    for (int i = 0; i < 18; ++i)
        if (i < ntile) {
#pragma unroll
            for (int r = 0; r < 4; ++r) {
                float p = __expf(sreg[i][r] - mx[r]);
                sm[r] += p;
                Pl[w][quad * 4 + r][i * 16 + l16] = f2bf(p);
            }
        }
#pragma unroll
    for (int r = 0; r < 4; ++r) {
#pragma unroll
        for (int o = 8; o >= 1; o >>= 1) sm[r] += __shfl_xor(sm[r], o, 64);
        sm[r] = 1.0f / sm[r];
    }

    // ---- PV ----
    f32x4 oacc[4] = {};
    const unsigned short* vbase = vbT + (size_t)nh * 64 * SEQ;
#pragma unroll
    for (int kc = 0; kc < 9; ++kc) {
        if (kc < nchunk) {
            bf16x8 pf = *(const bf16x8*)&Pl[w][l16][kc * 32 + quad * 8];
            const int toff = klo + kc * 32 + quad * 8;
#pragma unroll
            for (int j = 0; j < 4; ++j) {
                bf16x8 vf = *(const bf16x8*)(vbase + (size_t)(j * 16 + l16) * SEQ + toff);
                oacc[j] = __builtin_amdgcn_mfma_f32_16x16x32_bf16(pf, vf, oacc[j], 0, 0, 0);
            }
        }
    }

    // ---- normalize + store ----
#pragma unroll
    for (int j = 0; j < 4; ++j)
#pragma unroll
        for (int r = 0; r < 4; ++r) {
            const int t = tw + quad * 4 + r;
            attnb[((size_t)(nB * SEQ + t)) * D_MODEL + h * 64 + j * 16 + l16] =
                f2bf(oacc[j][r] * sm[r]);
        }
}

// ---------------------------------------------------------------------------
extern "C" void kernel_launch(void* const* d_in, const int* in_sizes, int n_in,
                              void* d_out, int out_size, void* d_ws, size_t ws_size,
                              hipStream_t stream)
{
    (void)in_sizes; (void)n_in; (void)out_size; (void)ws_size;
    const float* x     = (const float*)d_in[0];
    const float* w_qkv = (const float*)d_in[1];
    const float* w_out = (const float*)d_in[2];
    const float* b_out = (const float*)d_in[3];
    float* out = (float*)d_out;

    const int M = BATCH * SEQ;                 // 4096

    // ws layout (ushorts), 41.9 MB total:
    //   qb | kb | vbT | wob | xb | wqb   (attnb reuses xb after QKV GEMM)
    unsigned short* qb  = (unsigned short*)d_ws;
    unsigned short* kb  = qb  + (size_t)4194304;
    unsigned short* vbT = kb  + (size_t)4194304;
    unsigned short* wob = vbT + (size_t)4194304;
    unsigned short* xb  = wob + (size_t)1048576;
    unsigned short* wqb = xb  + (size_t)4194304;
    unsigned short* attnb = xb;

    dim3 blk(256);

    // 0) fp32 -> bf16 conversions (single launch)
    cvt_all<<<dim3((NX_ELEM + NW_ELEM + NO_ELEM) / 4 / 256), blk, 0, stream>>>(
        x, w_qkv, w_out, xb, wqb, wob);

    // 1) fused QKV projection + RoPE -> qb,kb [n,h,t,64], vbT [n,h,64,t] (bf16)
    gemm_qkv<<<dim3(3 * D_MODEL / 128, M / 128), blk, 0, stream>>>(
        xb, wqb, qb, kb, vbT, M, 3 * D_MODEL, D_MODEL);

    // 2) banded MFMA attention -> attnb [n,t,D] bf16
    attn_mfma<<<dim3(SEQ / 64, N_HEADS, BATCH), blk, 0, stream>>>(qb, kb, vbT, attnb);

    // 3) out = attn @ w_out^T + b_out
    gemm_out<<<dim3(D_MODEL / 128, M / 128), blk, 0, stream>>>(
        attnb, wob, b_out, out, M, D_MODEL, D_MODEL);
}